// Round 2
// baseline (543.248 us; speedup 1.0000x reference)
//
#include <hip/hip_runtime.h>
#include <hip/hip_bf16.h>

// RNN: h_t = tanh(x_t U + h_{t-1} W + b), return h_T.  B=256 T=512 D=K=256.
// Phase 0: transpose U -> Ut fp16 [256][264] in ws (for contiguous-k B-frag staging).
// Phase 1: xU = x @ U  as fp16, layout [T][B][K] (row-major with m = t*256+b) in ws.
// Phase 2: 16 blocks x 16 batch rows; W held in VGPRs as MFMA B-frags for all 512
//          steps; h ping-pongs through padded LDS; xU prefetched 1 step ahead.

typedef _Float16 half8_t __attribute__((ext_vector_type(8)));
typedef _Float16 half2_t __attribute__((ext_vector_type(2)));
typedef float    float4_t __attribute__((ext_vector_type(4)));

#define MFMA16(a, b, c) __builtin_amdgcn_mfma_f32_16x16x32_f16((a), (b), (c), 0, 0, 0)

__device__ __forceinline__ half2_t pk_h2(float a, float b) {
    // cvt_pkrtz returns __fp16x2; bit-identical to _Float16x2 — bit_cast it.
    auto r = __builtin_amdgcn_cvt_pkrtz(a, b);
    return __builtin_bit_cast(half2_t, r);
}

__device__ __forceinline__ float fast_tanh(float x) {
    // tanh(x) = 1 - 2/(e^{2x}+1); exp overflow -> inf -> 1, underflow -> 0 -> -1. OK.
    float e = __expf(2.0f * x);
    return 1.0f - 2.0f * __builtin_amdgcn_rcpf(e + 1.0f);
}

// ---------------- Phase 0: U[d][n] fp32 -> Ut[n][d] fp16 (row stride 264) ----------
__global__ void transpose_u(const float* __restrict__ U, _Float16* __restrict__ Ut) {
    int id = blockIdx.x * 256 + threadIdx.x;   // 65536 elements
    int d = id >> 8, n = id & 255;
    Ut[n * 264 + d] = (_Float16)U[id];
}

// ---------------- Phase 1: xU GEMM, 128x256 tile, BK=32, dbuf LDS ------------------
// grid 1024: t_blk = bx>>1 (t fixed per tile), b0 = (bx&1)*128. Output row m = t*256+b.
__global__ __launch_bounds__(256, 2) void xu_gemm(
    const float* __restrict__ x,        // [256][512][256] fp32
    const _Float16* __restrict__ Ut,    // [256][264] fp16
    half2_t* __restrict__ xu)           // [131072][128] half2 (= [T*B][256] halves)
{
    __shared__ char lds[61440];  // As[2][128*80B] @0, Bs[2][256*80B] @20480
    const int tid = threadIdx.x;
    const int lane = tid & 63, w = tid >> 6, l15 = lane & 15, q = lane >> 4;
    const int bx = blockIdx.x;
    const int t_blk = bx >> 1;
    const int b0 = (bx & 1) * 128;

    float4 ar[4];
    uint4  br[4];

    auto loadA = [&](int it) {
#pragma unroll
        for (int i = 0; i < 4; ++i) {
            int u = tid + 256 * i, row = u >> 3, seg = u & 7;
            ar[i] = *(const float4*)(x + ((size_t)(b0 + row) * 512 + t_blk) * 256
                                       + it * 32 + seg * 4);
        }
    };
    auto loadB = [&](int it) {
#pragma unroll
        for (int i = 0; i < 4; ++i) {
            int u = tid + 256 * i, p = u >> 2, seg = u & 3;
            // column-interleaved slot -> actual U column (for packed epilogue stores)
            int c = 32 * (p >> 5) + 2 * (p & 15) + ((p >> 4) & 1);
            br[i] = *(const uint4*)((const char*)Ut + c * 528 + it * 64 + seg * 16);
        }
    };
    auto writeAB = [&](int s) {
        char* As = lds + s * 10240;
        char* Bs = lds + 20480 + s * 20480;
#pragma unroll
        for (int i = 0; i < 4; ++i) {
            int u = tid + 256 * i, row = u >> 3, seg = u & 7;
            half2_t p0 = pk_h2(ar[i].x, ar[i].y);
            half2_t p1 = pk_h2(ar[i].z, ar[i].w);
            uint2 v;
            v.x = __builtin_bit_cast(unsigned, p0);
            v.y = __builtin_bit_cast(unsigned, p1);
            *(uint2*)(As + row * 80 + seg * 8) = v;
        }
#pragma unroll
        for (int i = 0; i < 4; ++i) {
            int u = tid + 256 * i, p = u >> 2, seg = u & 3;
            *(uint4*)(Bs + p * 80 + seg * 16) = br[i];
        }
    };

    float4_t acc[32];
#pragma unroll
    for (int i = 0; i < 32; ++i) { acc[i][0] = 0.f; acc[i][1] = 0.f; acc[i][2] = 0.f; acc[i][3] = 0.f; }

    loadA(0); loadB(0); writeAB(0);
    __syncthreads();

    for (int it = 0; it < 8; ++it) {
        if (it < 7) { loadA(it + 1); loadB(it + 1); }
        const char* As = lds + (it & 1) * 10240;
        const char* Bs = lds + 20480 + (it & 1) * 20480;
        half8_t af[2];
#pragma unroll
        for (int ms = 0; ms < 2; ++ms)
            af[ms] = *(const half8_t*)(As + (32 * w + 16 * ms + l15) * 80 + q * 16);
#pragma unroll
        for (int ns = 0; ns < 16; ++ns) {
            half8_t bf = *(const half8_t*)(Bs + (16 * ns + l15) * 80 + q * 16);
            acc[ns * 2 + 0] = MFMA16(af[0], bf, acc[ns * 2 + 0]);
            acc[ns * 2 + 1] = MFMA16(af[1], bf, acc[ns * 2 + 1]);
        }
        if (it < 7) writeAB((it + 1) & 1);
        __syncthreads();
    }

    // epilogue: pack col pairs (interleaved tiles 2j/2j+1 -> cols c, c+1)
#pragma unroll
    for (int ms = 0; ms < 2; ++ms)
#pragma unroll
        for (int j = 0; j < 8; ++j)
#pragma unroll
            for (int i = 0; i < 4; ++i) {
                float v0 = acc[(2 * j) * 2 + ms][i];
                float v1 = acc[(2 * j + 1) * 2 + ms][i];
                half2_t p = pk_h2(v0, v1);
                int m_g = bx * 128 + 32 * w + 16 * ms + q * 4 + i;
                int c = 32 * j + 2 * l15;
                xu[(size_t)m_g * 128 + (c >> 1)] = p;
            }
}

// ---------------- Phase 2: 512-step scan, W stationary in VGPRs --------------------
// 16 blocks x 512 threads (8 waves). Wave w owns cols [32w,32w+32) as two
// column-interleaved 16-wide tiles (cols 32w+2l and 32w+2l+1).
__global__ __launch_bounds__(512, 2) void rnn_scan(
    const half2_t* __restrict__ xu,     // [T*256][128] half2
    const float* __restrict__ W,        // [256][256] fp32
    const float* __restrict__ bias,     // [256]
    float* __restrict__ out)            // [256][256] fp32
{
    __shared__ char lds[16896];         // h dbuf: 2 x (16 rows x 528B: 256 f16 + 8 pad)
    const int tid = threadIdx.x;
    const int lane = tid & 63, w = tid >> 6, l15 = lane & 15, q = lane >> 4;
    const int blk = blockIdx.x;         // 0..15 -> rows 16*blk..+15
    const int c0 = 32 * w + 2 * l15;    // even column of this lane's tile pair

    // one-time: W -> B-frags in registers (each (k,col) loaded by exactly one lane)
    half8_t wf[2][8];
#pragma unroll
    for (int tt = 0; tt < 2; ++tt)
#pragma unroll
        for (int c = 0; c < 8; ++c) {
            half8_t f;
#pragma unroll
            for (int j = 0; j < 8; ++j) {
                int k = 32 * c + q * 8 + j;
                f[j] = (_Float16)W[k * 256 + c0 + tt];
            }
            wf[tt][c] = f;
        }
    const float b0 = bias[c0], b1 = bias[c0 + 1];

    // h0 = 0
    for (int i = tid; i < 16896 / 4; i += 512) ((int*)lds)[i] = 0;

    const int rowg0 = 16 * blk + q * 4;          // + i gives this lane's C rows
    // prefetch xU for t=0
    half2_t xu_n[4];
    {
        int xb = (0 * 256 + rowg0) * 128 + (c0 >> 1);
#pragma unroll
        for (int i = 0; i < 4; ++i) xu_n[i] = xu[xb + i * 128];
    }
    __syncthreads();

    char* const hbuf0 = (char*)lds;
    char* const hbuf1 = (char*)lds + 8448;

    for (int t = 0; t < 512; ++t) {
        float4_t acc0, acc1;
#pragma unroll
        for (int i = 0; i < 4; ++i) { acc0[i] = (float)xu_n[i][0]; acc1[i] = (float)xu_n[i][1]; }

        // prefetch next step's xU early (hidden under MFMA + this step's barrier)
        int tn = (t < 511) ? (t + 1) : 511;
        int xb = (tn * 256 + rowg0) * 128 + (c0 >> 1);
#pragma unroll
        for (int i = 0; i < 4; ++i) xu_n[i] = xu[xb + i * 128];

        const char* hcur = (t & 1) ? hbuf1 : hbuf0;
        half8_t af[8];
#pragma unroll
        for (int c = 0; c < 8; ++c)
            af[c] = *(const half8_t*)(hcur + l15 * 528 + c * 64 + q * 16);

#pragma unroll
        for (int c = 0; c < 8; ++c) {
            acc0 = MFMA16(af[c], wf[0][c], acc0);
            acc1 = MFMA16(af[c], wf[1][c], acc1);
        }

        if (t == 511) {
#pragma unroll
            for (int i = 0; i < 4; ++i) {
                float v0 = fast_tanh(acc0[i] + b0);
                float v1 = fast_tanh(acc1[i] + b1);
                float2 st; st.x = v0; st.y = v1;
                *(float2*)(&out[(rowg0 + i) * 256 + c0]) = st;
            }
        } else {
            char* hnext = ((t + 1) & 1) ? hbuf1 : hbuf0;
#pragma unroll
            for (int i = 0; i < 4; ++i) {
                float v0 = fast_tanh(acc0[i] + b0);
                float v1 = fast_tanh(acc1[i] + b1);
                half2_t p = pk_h2(v0, v1);
                *(half2_t*)(hnext + (q * 4 + i) * 528 + c0 * 2) = p;
            }
        }
        __syncthreads();
    }
}

extern "C" void kernel_launch(void* const* d_in, const int* in_sizes, int n_in,
                              void* d_out, int out_size, void* d_ws, size_t ws_size,
                              hipStream_t stream) {
    const float* x = (const float*)d_in[0];   // [256,512,256]
    const float* U = (const float*)d_in[1];   // [256,256]
    const float* W = (const float*)d_in[2];   // [256,256]
    const float* b = (const float*)d_in[3];   // [256]
    float* out = (float*)d_out;

    char* ws = (char*)d_ws;
    _Float16* Ut = (_Float16*)ws;                       // 256*264*2 = 135168 B
    half2_t*  xu = (half2_t*)(ws + 262144);             // 512*256*256*2 = 67,108,864 B
    // requires ws_size >= 67,371,008 B

    transpose_u<<<256, 256, 0, stream>>>(U, Ut);
    xu_gemm<<<1024, 256, 0, stream>>>(x, Ut, xu);
    rnn_scan<<<16, 512, 0, stream>>>(xu, W, b, out);
}